// Round 1
// baseline (145.639 us; speedup 1.0000x reference)
//
#include <hip/hip_runtime.h>
#include <stdint.h>

#define BATCH 32
#define NBOX 8192
#define NGT 128
#define M (NBOX + NGT)     // 8320
#define K_OUT 512
#define MAX_FG 128

// ---------------------------------------------------------------------------
// Kernel 1: per (b, m) compute max IoU over 128 gt boxes + argmax, pack flags.
// packed[b*M+m] = argmax | (neg<<8) | (pos<<9)
// All float arithmetic via __f*_rn to forbid FMA contraction (must match numpy).
// ---------------------------------------------------------------------------
__global__ __launch_bounds__(256) void iou_kernel(
    const float* __restrict__ boxes,      // [B, NBOX, 4]
    const float* __restrict__ gt_boxes,   // [B, NGT, 4]
    int* __restrict__ packed)             // [B, M]
{
    const int BPB = (M + 255) / 256;      // 33 blocks per batch
    const int b = blockIdx.x / BPB;
    const int m = (blockIdx.x % BPB) * 256 + threadIdx.x;

    __shared__ float4 sgt[NGT];
    __shared__ float  sgarea[NGT];
    if (threadIdx.x < NGT) {
        float4 g = ((const float4*)gt_boxes)[b * NGT + threadIdx.x];
        sgt[threadIdx.x] = g;
        sgarea[threadIdx.x] = __fmul_rn(__fsub_rn(g.z, g.x), __fsub_rn(g.w, g.y));
    }
    __syncthreads();
    if (m >= M) return;

    float4 bb = (m < NBOX) ? ((const float4*)boxes)[b * NBOX + m]
                           : ((const float4*)gt_boxes)[b * NGT + (m - NBOX)];
    float b_area = __fmul_rn(__fsub_rn(bb.z, bb.x), __fsub_rn(bb.w, bb.y));

    float best = -1e30f;
    int bidx = 0;
    #pragma unroll 4
    for (int g = 0; g < NGT; ++g) {
        float4 gg = sgt[g];
        float iymin = fmaxf(bb.x, gg.x);
        float ixmin = fmaxf(bb.y, gg.y);
        float iymax = fminf(bb.z, gg.z);
        float ixmax = fminf(bb.w, gg.w);
        float ia  = __fmul_rn(fmaxf(__fsub_rn(iymax, iymin), 0.0f),
                              fmaxf(__fsub_rn(ixmax, ixmin), 0.0f));
        float den = __fsub_rn(__fadd_rn(b_area, sgarea[g]), ia);
        float iou = __fdiv_rn(ia, den);
        if (iymin < 0.0f && ixmin < 0.0f) iou = -1.0f;   // padded-gt clause
        if (iou > best) { best = iou; bidx = g; }        // first-max = argmax
    }
    bool pos = best > 0.5f;
    bool neg = (best >= 0.0f) && (best < 0.5f);
    packed[b * M + m] = bidx | (neg ? 256 : 0) | (pos ? 512 : 0);
}

// Monotone float->uint map (ascending order preserved, incl. negatives).
__device__ __forceinline__ unsigned int fmap(float f) {
    unsigned int u = __float_as_uint(f);
    return (u & 0x80000000u) ? ~u : (u | 0x80000000u);
}

// 64-bit sort key: value desc primary, index asc secondary, all keys distinct.
__device__ __forceinline__ unsigned long long make_key(
    int pkv, float nsv, int m, unsigned int kth_mapped)
{
    bool pos = (pkv & 512) != 0;
    bool neg = (pkv & 256) != 0;
    bool selp = pos && ((__float_as_uint(nsv) | 0x80000000u) >= kth_mapped);
    float c = selp ? __fadd_rn(2.0f, nsv) : (neg ? nsv : -1.0f);
    unsigned int mc = fmap(c);
    return ((unsigned long long)mc << 32) |
           (unsigned long long)(0xFFFFFFFFu - (unsigned int)m);
}

// ---------------------------------------------------------------------------
// Kernel 2: one block per batch. Steps:
//  (1) exact 128th-largest pos_score (radix select, 4 passes, 8-bit digits)
//  (2) exact 512th-largest 64-bit combined key (8 passes)
//  (3) compact the 512 winners, bitonic-sort descending
//  (4) gather + write all 4 outputs (ints written as float)
// ---------------------------------------------------------------------------
__global__ __launch_bounds__(1024) void select_kernel(
    const float* __restrict__ boxes,
    const float* __restrict__ gt_boxes,
    const int*   __restrict__ gt_labels,
    const float* __restrict__ noise,      // [B, M]
    const int*   __restrict__ packed,     // [B, M]
    float* __restrict__ out)
{
    const int b = blockIdx.x;
    const int tid = threadIdx.x;
    __shared__ unsigned int hist[256];
    __shared__ unsigned long long cand[K_OUT];
    __shared__ unsigned long long sh_prefix;
    __shared__ unsigned int sh_k;

    const int*   pk = packed + b * M;
    const float* ns = noise  + b * M;

    // ---- (1) kth = 128th largest pos_score (value select over mapped32) ----
    if (tid == 0) { sh_prefix = 0ull; sh_k = MAX_FG; }
    for (int p = 3; p >= 0; --p) {
        __syncthreads();
        if (tid < 256) hist[tid] = 0;
        __syncthreads();
        unsigned long long pref = sh_prefix;
        int sh = (p + 1) * 8;  // <= 32, fine on u64
        for (int m = tid; m < M; m += 1024) {
            unsigned int mapped = (pk[m] & 512)
                ? (__float_as_uint(ns[m]) | 0x80000000u)   // noise >= 0
                : 0x407FFFFFu;                              // fmap(-1.0f)
            unsigned long long key = mapped;
            if ((key >> sh) == (pref >> sh))
                atomicAdd(&hist[(unsigned int)(key >> (p * 8)) & 0xFFu], 1u);
        }
        __syncthreads();
        // suffix-sum scan: hist[d] := sum_{j>=d} hist[j]
        for (int off = 1; off < 256; off <<= 1) {
            unsigned int v = 0;
            if (tid < 256) v = hist[tid] + ((tid + off < 256) ? hist[tid + off] : 0);
            __syncthreads();
            if (tid < 256) hist[tid] = v;
            __syncthreads();
        }
        unsigned int kk = sh_k;
        __syncthreads();
        if (tid < 256) {
            unsigned int cum = hist[tid];
            unsigned int cumAbove = (tid < 255) ? hist[tid + 1] : 0;
            if (cum >= kk && cumAbove < kk) {
                sh_k = kk - cumAbove;
                sh_prefix = pref | ((unsigned long long)tid << (p * 8));
            }
        }
    }
    __syncthreads();
    const unsigned int kth_mapped = (unsigned int)sh_prefix;
    __syncthreads();

    // ---- (2) 512th-largest 64-bit key ----
    if (tid == 0) { sh_prefix = 0ull; sh_k = K_OUT; }
    for (int p = 7; p >= 0; --p) {
        __syncthreads();
        if (tid < 256) hist[tid] = 0;
        __syncthreads();
        unsigned long long pref = sh_prefix;
        int sh = (p + 1) * 8;
        for (int m = tid; m < M; m += 1024) {
            unsigned long long key = make_key(pk[m], ns[m], m, kth_mapped);
            bool match = (p == 7) ? true : ((key >> sh) == (pref >> sh));
            if (match)
                atomicAdd(&hist[(unsigned int)(key >> (p * 8)) & 0xFFu], 1u);
        }
        __syncthreads();
        for (int off = 1; off < 256; off <<= 1) {
            unsigned int v = 0;
            if (tid < 256) v = hist[tid] + ((tid + off < 256) ? hist[tid + off] : 0);
            __syncthreads();
            if (tid < 256) hist[tid] = v;
            __syncthreads();
        }
        unsigned int kk = sh_k;
        __syncthreads();
        if (tid < 256) {
            unsigned int cum = hist[tid];
            unsigned int cumAbove = (tid < 255) ? hist[tid + 1] : 0;
            if (cum >= kk && cumAbove < kk) {
                sh_k = kk - cumAbove;
                sh_prefix = pref | ((unsigned long long)tid << (p * 8));
            }
        }
    }
    __syncthreads();
    const unsigned long long thresh = sh_prefix;   // exact 512th-largest key
    __syncthreads();

    // ---- (3) compact winners (keys distinct => exactly 512 pass) ----
    if (tid == 0) sh_k = 0;
    __syncthreads();
    for (int m = tid; m < M; m += 1024) {
        unsigned long long key = make_key(pk[m], ns[m], m, kth_mapped);
        if (key >= thresh) {
            unsigned int slot = atomicAdd(&sh_k, 1u);
            if (slot < K_OUT) cand[slot] = key;
        }
    }
    __syncthreads();

    // bitonic sort, descending, n=512
    for (int size = 2; size <= K_OUT; size <<= 1) {
        for (int stride = size >> 1; stride > 0; stride >>= 1) {
            __syncthreads();
            if (tid < K_OUT) {
                int i = tid, j = i ^ stride;
                if (j > i) {
                    bool up = ((i & size) == 0);   // descending segment
                    unsigned long long a = cand[i], c = cand[j];
                    bool sw = up ? (a < c) : (a > c);
                    if (sw) { cand[i] = c; cand[j] = a; }
                }
            }
        }
    }
    __syncthreads();

    // ---- (4) gather + write ----
    if (tid < K_OUT) {
        unsigned long long key = cand[tid];
        unsigned int m = 0xFFFFFFFFu - (unsigned int)(key & 0xFFFFFFFFull);
        int pkv = pk[m];
        bool neg = (pkv & 256) != 0;
        int lbl = pkv & 255;

        float4 roi = (m < NBOX) ? ((const float4*)boxes)[b * NBOX + m]
                                : ((const float4*)gt_boxes)[b * NGT + (m - NBOX)];
        float4 bt = make_float4(0.0f, 0.0f, 0.0f, 0.0f);
        int cls = 0, pout = 0;
        if (!neg) {
            bt   = ((const float4*)gt_boxes)[b * NGT + lbl];
            cls  = gt_labels[b * NGT + lbl];
            pout = lbl;
        }
        // output layout (floats): box_t [B,512,4] | cls_t [B,512] | rois [B,512,4] | p2l [B,512]
        float* out_bt  = out;
        float* out_cls = out + BATCH * K_OUT * 4;
        float* out_roi = out + BATCH * K_OUT * 5;
        float* out_p2l = out + BATCH * K_OUT * 9;
        ((float4*)out_bt)[b * K_OUT + tid] = bt;
        out_cls[b * K_OUT + tid] = (float)cls;
        ((float4*)out_roi)[b * K_OUT + tid] = roi;
        out_p2l[b * K_OUT + tid] = (float)pout;
    }
}

extern "C" void kernel_launch(void* const* d_in, const int* in_sizes, int n_in,
                              void* d_out, int out_size, void* d_ws, size_t ws_size,
                              hipStream_t stream) {
    const float* boxes     = (const float*)d_in[0];
    const float* gt_boxes  = (const float*)d_in[1];
    const int*   gt_labels = (const int*)d_in[2];
    const float* noise     = (const float*)d_in[3];
    int* packed = (int*)d_ws;          // B*M ints = 1,064,960 B of scratch
    float* out  = (float*)d_out;

    const int BPB = (M + 255) / 256;   // 33
    iou_kernel<<<BATCH * BPB, 256, 0, stream>>>(boxes, gt_boxes, packed);
    select_kernel<<<BATCH, 1024, 0, stream>>>(boxes, gt_boxes, gt_labels, noise,
                                              packed, out);
}

// Round 2
// 118.465 us; speedup vs baseline: 1.2294x; 1.2294x over previous
//
#include <hip/hip_runtime.h>
#include <stdint.h>

#define BATCH 32
#define NBOX 8192
#define NGT 128
#define M (NBOX + NGT)     // 8320
#define K_OUT 512
#define MAX_FG 128
#define A_CAP 1536

// ---------------------------------------------------------------------------
// Kernel 1: per (b, m) compute max IoU over 128 gt boxes + argmax, pack flags.
// packed[b*M+m] = argmax | (neg<<8) | (pos<<9)
// All float arithmetic via __f*_rn to forbid FMA contraction (must match numpy).
// (unchanged from R1 — verified exact, absmax 0.0)
// ---------------------------------------------------------------------------
__global__ __launch_bounds__(256) void iou_kernel(
    const float* __restrict__ boxes,      // [B, NBOX, 4]
    const float* __restrict__ gt_boxes,   // [B, NGT, 4]
    int* __restrict__ packed)             // [B, M]
{
    const int BPB = (M + 255) / 256;      // 33 blocks per batch
    const int b = blockIdx.x / BPB;
    const int m = (blockIdx.x % BPB) * 256 + threadIdx.x;

    __shared__ float4 sgt[NGT];
    __shared__ float  sgarea[NGT];
    if (threadIdx.x < NGT) {
        float4 g = ((const float4*)gt_boxes)[b * NGT + threadIdx.x];
        sgt[threadIdx.x] = g;
        sgarea[threadIdx.x] = __fmul_rn(__fsub_rn(g.z, g.x), __fsub_rn(g.w, g.y));
    }
    __syncthreads();
    if (m >= M) return;

    float4 bb = (m < NBOX) ? ((const float4*)boxes)[b * NBOX + m]
                           : ((const float4*)gt_boxes)[b * NGT + (m - NBOX)];
    float b_area = __fmul_rn(__fsub_rn(bb.z, bb.x), __fsub_rn(bb.w, bb.y));

    float best = -1e30f;
    int bidx = 0;
    #pragma unroll 4
    for (int g = 0; g < NGT; ++g) {
        float4 gg = sgt[g];
        float iymin = fmaxf(bb.x, gg.x);
        float ixmin = fmaxf(bb.y, gg.y);
        float iymax = fminf(bb.z, gg.z);
        float ixmax = fminf(bb.w, gg.w);
        float ia  = __fmul_rn(fmaxf(__fsub_rn(iymax, iymin), 0.0f),
                              fmaxf(__fsub_rn(ixmax, ixmin), 0.0f));
        float den = __fsub_rn(__fadd_rn(b_area, sgarea[g]), ia);
        float iou = __fdiv_rn(ia, den);
        if (iymin < 0.0f && ixmin < 0.0f) iou = -1.0f;   // padded-gt clause
        if (iou > best) { best = iou; bidx = g; }        // first-max = argmax
    }
    bool pos = best > 0.5f;
    bool neg = (best >= 0.0f) && (best < 0.5f);
    packed[b * M + m] = bidx | (neg ? 256 : 0) | (pos ? 512 : 0);
}

// Monotone float->uint map (ascending order preserved, incl. negatives).
__device__ __forceinline__ unsigned int fmap(float f) {
    unsigned int u = __float_as_uint(f);
    return (u & 0x80000000u) ? ~u : (u | 0x80000000u);
}

// ---------------------------------------------------------------------------
// Kernel 2: one block (1024 thr) per batch.
//  LDS-resident single-load design; uniform bucketing on (uint)(noise*2^24)>>16
//  so histogram atomics are spread (~30/bin); exact boundary resolution and
//  final ordering via exact (mc<<32 | ~m) 64-bit keys + pairwise ranking.
// ---------------------------------------------------------------------------
__global__ __launch_bounds__(1024) void select_kernel(
    const float* __restrict__ boxes,
    const float* __restrict__ gt_boxes,
    const int*   __restrict__ gt_labels,
    const float* __restrict__ noise,      // [B, M]
    const int*   __restrict__ packed,     // [B, M]
    float* __restrict__ out)
{
    const int b = blockIdx.x;
    const int tid = threadIdx.x;

    __shared__ unsigned long long A[A_CAP];       // 12288 B (also aliased u32)
    __shared__ float sh_ns[M];                    // 33280 B
    __shared__ unsigned char sh_fl[M];            // 8320 B  (bit0=neg, bit1=pos)
    __shared__ unsigned int hist[1024];           // 4096 B
    __shared__ unsigned int sh_B, sh_need, sh_cnt, sh_kth;

    unsigned int* A32 = (unsigned int*)A;

    // --- step 1: zero hist -------------------------------------------------
    hist[tid] = 0;
    __syncthreads();

    // --- step 2: load pass (global -> LDS) + pos-noise histogram -----------
    {
        const float4* ns4 = (const float4*)(noise + b * M);
        const int4*   pk4 = (const int4*)(packed + b * M);
        for (int c = tid; c < M / 4; c += 1024) {
            float4 nv = ns4[c];
            int4   pv = pk4[c];
            ((float4*)sh_ns)[c] = nv;
            uchar4 fl;
            fl.x = (unsigned char)((pv.x >> 8) & 3);
            fl.y = (unsigned char)((pv.y >> 8) & 3);
            fl.z = (unsigned char)((pv.z >> 8) & 3);
            fl.w = (unsigned char)((pv.w >> 8) & 3);
            ((uchar4*)sh_fl)[c] = fl;
            if (pv.x & 512) atomicAdd(&hist[(unsigned int)(nv.x * 16777216.0f) >> 16], 1u);
            if (pv.y & 512) atomicAdd(&hist[(unsigned int)(nv.y * 16777216.0f) >> 16], 1u);
            if (pv.z & 512) atomicAdd(&hist[(unsigned int)(nv.z * 16777216.0f) >> 16], 1u);
            if (pv.w & 512) atomicAdd(&hist[(unsigned int)(nv.w * 16777216.0f) >> 16], 1u);
        }
    }
    __syncthreads();

    // --- step 3: suffix scan of hist by wave 0 (shfl, no extra barriers) ---
    if (tid < 64) {
        unsigned int s[16];
        #pragma unroll
        for (int c = 0; c < 16; ++c) {
            unsigned int v = hist[c * 64 + tid];
            #pragma unroll
            for (int off = 1; off < 64; off <<= 1) {
                unsigned int o = __shfl_down(v, off, 64);
                if (tid + off < 64) v += o;
            }
            s[c] = v;    // inclusive suffix within 64-bin chunk
        }
        unsigned int after = 0;
        #pragma unroll
        for (int c = 15; c >= 0; --c) {
            unsigned int tot = __shfl(s[c], 0, 64);
            hist[c * 64 + tid] = s[c] + after;
            after += tot;
        }
    }
    __syncthreads();

    // --- step 4: kth = 128th-largest pos noise (exact value) ---------------
    const unsigned int np = hist[0];              // uniform across block
    if (np >= MAX_FG) {
        {   // boundary bucket for rank 128 (unique writer)
            unsigned int S  = hist[tid];
            unsigned int Sn = (tid < 1023) ? hist[tid + 1] : 0;
            if (S >= MAX_FG && Sn < MAX_FG) { sh_B = tid; sh_need = MAX_FG - Sn; }
        }
        __syncthreads();
        const unsigned int Bp = sh_B, need_p = sh_need;
        if (tid == 0) sh_cnt = 0;
        __syncthreads();
        // collect pos elements in boundary bucket (expected ~np/256)
        for (int m = tid; m < M; m += 1024) {
            if (sh_fl[m] & 2) {
                float ns = sh_ns[m];
                if (((unsigned int)(ns * 16777216.0f) >> 16) == Bp) {
                    unsigned int slot = atomicAdd(&sh_cnt, 1u);
                    if (slot < A_CAP * 2) A32[slot] = __float_as_uint(ns);
                }
            }
        }
        __syncthreads();
        {   // exact value-rank: kth value v has  #greater < need_p <= #greater+#eq
            unsigned int ncp = min(sh_cnt, (unsigned int)(A_CAP * 2));
            if (tid < ncp) {
                unsigned int my = A32[tid];
                unsigned int g = 0, e = 0;
                for (unsigned int j = 0; j < ncp; ++j) {
                    unsigned int v = A32[j];
                    g += (v > my) ? 1u : 0u;
                    e += (v == my) ? 1u : 0u;
                }
                if (g < need_p && g + e >= need_p) sh_kth = my;  // same-value writers
            }
        }
    } else {
        if (tid == 0) sh_kth = 0xBF800000u;       // -1.0f : all pos selected
    }
    __syncthreads();
    const float kthf = __uint_as_float(sh_kth);

    // --- step 5: full-key histogram (3 bands: rest < neg < selp) -----------
    hist[tid] = 0;
    __syncthreads();
    for (int m = tid; m < M; m += 1024) {
        float ns = sh_ns[m];
        unsigned char f = sh_fl[m];
        bool pos = (f & 2), neg = (f & 1);
        bool selp = pos && (ns >= kthf);
        unsigned int bkt;
        if (selp)      bkt = 386 + ((unsigned int)(ns * 16777216.0f) >> 16);
        else if (neg)  bkt = 130 + ((unsigned int)(ns * 16777216.0f) >> 16);
        else           bkt = (unsigned int)(M - 1 - m) >> 6;   // m asc == key desc
        atomicAdd(&hist[bkt], 1u);
    }
    __syncthreads();

    // --- step 6: suffix scan again ------------------------------------------
    if (tid < 64) {
        unsigned int s[16];
        #pragma unroll
        for (int c = 0; c < 16; ++c) {
            unsigned int v = hist[c * 64 + tid];
            #pragma unroll
            for (int off = 1; off < 64; off <<= 1) {
                unsigned int o = __shfl_down(v, off, 64);
                if (tid + off < 64) v += o;
            }
            s[c] = v;
        }
        unsigned int after = 0;
        #pragma unroll
        for (int c = 15; c >= 0; --c) {
            unsigned int tot = __shfl(s[c], 0, 64);
            hist[c * 64 + tid] = s[c] + after;
            after += tot;
        }
    }
    __syncthreads();

    // --- step 7: rank-512 boundary bucket -----------------------------------
    {
        unsigned int S  = hist[tid];
        unsigned int Sn = (tid < 1023) ? hist[tid + 1] : 0;
        if (S >= K_OUT && Sn < K_OUT) { sh_B = tid; }
    }
    __syncthreads();
    const unsigned int B1 = sh_B;
    if (tid == 0) sh_cnt = 0;
    __syncthreads();

    // --- step 8: compact union (bins >= B1) with exact 64-bit keys ----------
    for (int m = tid; m < M; m += 1024) {
        float ns = sh_ns[m];
        unsigned char f = sh_fl[m];
        bool pos = (f & 2), neg = (f & 1);
        bool selp = pos && (ns >= kthf);
        unsigned int bkt;
        if (selp)      bkt = 386 + ((unsigned int)(ns * 16777216.0f) >> 16);
        else if (neg)  bkt = 130 + ((unsigned int)(ns * 16777216.0f) >> 16);
        else           bkt = (unsigned int)(M - 1 - m) >> 6;
        if (bkt >= B1) {
            float c = selp ? __fadd_rn(2.0f, ns) : (neg ? ns : -1.0f);
            unsigned long long key = ((unsigned long long)fmap(c) << 32)
                                   | (unsigned long long)(0xFFFFFFFFu - (unsigned int)m);
            unsigned int slot = atomicAdd(&sh_cnt, 1u);
            if (slot < A_CAP) A[slot] = key;
        }
    }
    __syncthreads();

    // --- step 9: exact pairwise rank (keys distinct) + gather/write ---------
    const unsigned int q = min(sh_cnt, (unsigned int)A_CAP);
    if (tid < (int)q) {
        unsigned long long key = A[tid];
        unsigned int r = 0;
        #pragma unroll 4
        for (unsigned int j = 0; j < q; ++j) r += (A[j] > key) ? 1u : 0u;
        if (r < K_OUT) {
            unsigned int m = 0xFFFFFFFFu - (unsigned int)(key & 0xFFFFFFFFull);
            int pkv = packed[b * M + m];
            bool neg = (pkv & 256) != 0;
            int lbl = pkv & 255;

            float4 roi = (m < NBOX) ? ((const float4*)boxes)[b * NBOX + m]
                                    : ((const float4*)gt_boxes)[b * NGT + (m - NBOX)];
            float4 bt = make_float4(0.0f, 0.0f, 0.0f, 0.0f);
            int cls = 0, pout = 0;
            if (!neg) {
                bt   = ((const float4*)gt_boxes)[b * NGT + lbl];
                cls  = gt_labels[b * NGT + lbl];
                pout = lbl;
            }
            // layout: box_t [B,512,4] | cls_t [B,512] | rois [B,512,4] | p2l [B,512]
            float* out_bt  = out;
            float* out_cls = out + BATCH * K_OUT * 4;
            float* out_roi = out + BATCH * K_OUT * 5;
            float* out_p2l = out + BATCH * K_OUT * 9;
            ((float4*)out_bt)[b * K_OUT + r] = bt;
            out_cls[b * K_OUT + r] = (float)cls;
            ((float4*)out_roi)[b * K_OUT + r] = roi;
            out_p2l[b * K_OUT + r] = (float)pout;
        }
    }
}

extern "C" void kernel_launch(void* const* d_in, const int* in_sizes, int n_in,
                              void* d_out, int out_size, void* d_ws, size_t ws_size,
                              hipStream_t stream) {
    const float* boxes     = (const float*)d_in[0];
    const float* gt_boxes  = (const float*)d_in[1];
    const int*   gt_labels = (const int*)d_in[2];
    const float* noise     = (const float*)d_in[3];
    int* packed = (int*)d_ws;          // B*M ints of scratch
    float* out  = (float*)d_out;

    const int BPB = (M + 255) / 256;   // 33
    iou_kernel<<<BATCH * BPB, 256, 0, stream>>>(boxes, gt_boxes, packed);
    select_kernel<<<BATCH, 1024, 0, stream>>>(boxes, gt_boxes, gt_labels, noise,
                                              packed, out);
}